// Round 2
// baseline (1733.534 us; speedup 1.0000x reference)
//
#include <hip/hip_runtime.h>
#include <math.h>

#define MDIM   4096
#define NSTEPS 199
#define NBLK   256     // one block per CU
#define NTHR   1024    // 16 waves
#define B1C    0.9f
#define B2C    0.999f
#define EPSC   1e-8f

typedef unsigned long long u64;

// Tagged u element: high 32 = step tag, low 32 = float bits. One 8-byte
// relaxed agent-scope atomic carries data AND readiness (self-validating).
__device__ __forceinline__ u64 pack_uv(float v, unsigned t) {
    return ((u64)t << 32) | (u64)__float_as_uint(v);
}
__device__ __forceinline__ float    unpack_v(u64 p) { return __uint_as_float((unsigned)p); }
__device__ __forceinline__ unsigned unpack_t(u64 p) { return (unsigned)(p >> 32); }

// ---------------------------------------------------------------------------
// Prep: Qs[i][j] = 0.5*(va[i][j] + va[j][i]), LDS-tiled transpose (validated).
// ---------------------------------------------------------------------------
__global__ void prep_qs(const float* __restrict__ va, float* __restrict__ Qs) {
    __shared__ float tile[32][33];
    const int j0 = blockIdx.x * 32;
    const int i0 = blockIdx.y * 32;
    const int tx = threadIdx.x, ty = threadIdx.y;

    for (int k = 0; k < 32; k += 8)
        tile[ty + k][tx] = va[(size_t)(j0 + ty + k) * MDIM + i0 + tx];
    __syncthreads();
    for (int k = 0; k < 32; k += 8) {
        int i = i0 + ty + k;
        float a = va[(size_t)i * MDIM + j0 + tx];
        float b = tile[tx][ty + k];          // va[j][i]
        Qs[(size_t)i * MDIM + j0 + tx] = 0.5f * (a + b);
    }
}

// ---------------------------------------------------------------------------
// Init: u0 tagged 0 with value 1-mean. u1 tagged with a sentinel that can
// never match any expected tag (0..198) -> no stale-tag aliasing, even
// across graph-replay launches.
// ---------------------------------------------------------------------------
__global__ void init_state(const float* __restrict__ mean,
                           u64* __restrict__ u0, u64* __restrict__ u1) {
    int i = blockIdx.x * blockDim.x + threadIdx.x;
    if (i < MDIM) {
        u0[i] = pack_uv(1.0f - mean[i], 0u);
        u1[i] = pack_uv(0.0f, 0xFFFFFFFFu);
    }
}

// ---------------------------------------------------------------------------
// Persistent cooperative kernel.
// Wave w of block b: holds Q[16b..16b+15][256w..256w+255] in 64 regs/lane
// (qreg[r] = that row's float4 at this lane's 4 columns). Per step:
//   - quad-sentinel spin: lanes (lane&3)==0 spin on ONE tagged element
//     (2KB/block/round of poll traffic); sentinel ok => its producer block
//     passed its barrier, so the lane's other 3 elements follow within ~100cy.
//   - verify loop fetches remaining elements, retrying only pending ones.
//   - dot: 64 FMAs/lane into 16 row-partials; 32-shuffle fold (rows and
//     lanes simultaneously) -> lane quad q holds local row q's partial;
//     16x16(+1 pad) LDS partial matrix; ONE __syncthreads; 4-shuffle
//     cross-wave fold gives row w's g in wave w.
//   - Adam state and u[row] (this wave's own previous publish) in registers.
//   - publish tagged u64. No flag array, no LDS staging of u.
// ---------------------------------------------------------------------------
__global__ __launch_bounds__(NTHR) void adam_persist(
        const float* __restrict__ Qs,
        u64* u0, u64* u1,
        const float* __restrict__ mean,
        float* __restrict__ w_out) {
    __shared__ float pr[2][16][17];   // [buf][wave][local row], +1 pad

    const int tid  = threadIdx.x;
    const int bid  = blockIdx.x;
    const int wave = tid >> 6;
    const int lane = tid & 63;
    const int row  = bid * 16 + wave;
    const int col0 = wave * 256 + lane * 4;    // this lane's 4-element segment

    // ---- one-time: Q fragment -> registers (64 regs/lane) ----
    float4 qreg[16];
#pragma unroll
    for (int r = 0; r < 16; ++r)
        qreg[r] = *(const float4*)(Qs + (size_t)(bid * 16 + r) * MDIM + col0);

    float m = 0.0f, v = 0.0f, b1p = 1.0f, b2p = 1.0f;
    const float mrow = mean[row];
    float ucur = 1.0f - mrow;                  // u[row] lives in registers
    const bool sentinel = (lane & 3) == 0;

    for (int t = 1; t <= NSTEPS; ++t) {
        u64* uin  = (t & 1) ? u0 : u1;         // t=1 reads u0 (tag 0)
        u64* uout = (t & 1) ? u1 : u0;
        const unsigned tg = (unsigned)(t - 1);
        const int b = t & 1;

        float uv0 = 0.f, uv1 = 0.f, uv2 = 0.f, uv3 = 0.f;

        // ---- phase 1: quad-sentinel spin (low-traffic readiness wait) ----
        {
            bool ok = !sentinel;
            u64 s0 = 0;
            int spin = 0;
            for (;;) {
                if (!ok) {
                    s0 = __hip_atomic_load(uin + col0, __ATOMIC_RELAXED,
                                           __HIP_MEMORY_SCOPE_AGENT);
                    ok = (unpack_t(s0) == tg);
                }
                if (__all(ok)) break;
                if (++spin > (1 << 18)) break;     // fail visibly, never hang
            }
            if (sentinel) uv0 = unpack_v(s0);
        }

        // ---- phase 2: fetch/verify remaining elements (short retries) ----
        {
            unsigned pending = sentinel ? 0xEu : 0xFu;
            int spin = 0;
            while (pending) {
                if (pending & 1u) {
                    u64 x = __hip_atomic_load(uin + col0 + 0, __ATOMIC_RELAXED,
                                              __HIP_MEMORY_SCOPE_AGENT);
                    if (unpack_t(x) == tg) { uv0 = unpack_v(x); pending &= ~1u; }
                }
                if (pending & 2u) {
                    u64 x = __hip_atomic_load(uin + col0 + 1, __ATOMIC_RELAXED,
                                              __HIP_MEMORY_SCOPE_AGENT);
                    if (unpack_t(x) == tg) { uv1 = unpack_v(x); pending &= ~2u; }
                }
                if (pending & 4u) {
                    u64 x = __hip_atomic_load(uin + col0 + 2, __ATOMIC_RELAXED,
                                              __HIP_MEMORY_SCOPE_AGENT);
                    if (unpack_t(x) == tg) { uv2 = unpack_v(x); pending &= ~4u; }
                }
                if (pending & 8u) {
                    u64 x = __hip_atomic_load(uin + col0 + 3, __ATOMIC_RELAXED,
                                              __HIP_MEMORY_SCOPE_AGENT);
                    if (unpack_t(x) == tg) { uv3 = unpack_v(x); pending &= ~8u; }
                }
                if (++spin > (1 << 18)) break;     // fail visibly, never hang
            }
        }

        // ---- 16 row-partials over this lane's 4 columns ----
        float acc[16];
#pragma unroll
        for (int r = 0; r < 16; ++r) {
            float4 q = qreg[r];
            acc[r] = q.x * uv0 + q.y * uv1 + q.z * uv2 + q.w * uv3;
        }

        // ---- fold 16 values x 64 lanes -> 1 value/lane (32 shuffles) ----
        // After stage over mask M: high-half lanes keep the upper rows.
        // Final: lane quad q = (lane>>2) holds local row q, summed over the
        // 16 lanes sharing (lane&3).
#pragma unroll
        for (int stage = 0; stage < 4; ++stage) {
            const int mask = 32 >> stage;
            const int half = 8 >> stage;
            const bool hi = (lane & mask) != 0;
#pragma unroll
            for (int i = 0; i < half; ++i) {
                float plo = __shfl_xor(acc[i],        mask);
                float phi = __shfl_xor(acc[i + half], mask);
                acc[i] = hi ? (acc[i + half] + phi) : (acc[i] + plo);
            }
        }
        float acc0 = acc[0];
        acc0 += __shfl_xor(acc0, 1);   // finish sum within the quad
        acc0 += __shfl_xor(acc0, 2);

        if ((lane & 3) == 0) pr[b][wave][lane >> 2] = acc0;
        __syncthreads();               // the ONLY barrier per step

        // ---- cross-wave fold: wave w reduces local row w ----
        float unew = ucur;
        if (lane < 16) {
            float p = pr[b][lane][wave];
            p += __shfl_xor(p, 1);
            p += __shfl_xor(p, 2);
            p += __shfl_xor(p, 4);
            p += __shfl_xor(p, 8);
            const float g = p;

            b1p *= B1C;
            b2p *= B2C;
            m = B1C * m + (1.0f - B1C) * g;
            v = B2C * v + (1.0f - B2C) * g * g;
            const float denom = sqrtf(v) / sqrtf(1.0f - b2p) + EPSC;
            unew = ucur - (0.1f / (1.0f - b1p)) * m / denom;
            ucur = unew;
        }

        if (lane == 0)
            __hip_atomic_store(uout + row, pack_uv(unew, (unsigned)t),
                               __ATOMIC_RELAXED, __HIP_MEMORY_SCOPE_AGENT);
    }

    if (lane == 0) w_out[row] = ucur + mrow;
}

extern "C" void kernel_launch(void* const* d_in, const int* in_sizes, int n_in,
                              void* d_out, int out_size, void* d_ws, size_t ws_size,
                              hipStream_t stream) {
    const float* mean = (const float*)d_in[0];   // (4096,)
    const float* va   = (const float*)d_in[1];   // (4096,4096)
    float* w_out = (float*)d_out;                // (4096,)

    float* ws = (float*)d_ws;
    float* Qs = ws;                               // 64 MB
    u64*   u0 = (u64*)(ws + (size_t)MDIM * MDIM); // 32 KB tagged
    u64*   u1 = u0 + MDIM;                        // 32 KB tagged

    prep_qs<<<dim3(MDIM / 32, MDIM / 32), dim3(32, 8), 0, stream>>>(va, Qs);
    init_state<<<(MDIM + 255) / 256, 256, 0, stream>>>(mean, u0, u1);

    void* args[] = { (void*)&Qs, (void*)&u0, (void*)&u1,
                     (void*)&mean, (void*)&w_out };
    hipLaunchCooperativeKernel((const void*)adam_persist,
                               dim3(NBLK), dim3(NTHR), args, 0, stream);
}

// Round 3
// 967.550 us; speedup vs baseline: 1.7917x; 1.7917x over previous
//
#include <hip/hip_runtime.h>
#include <math.h>

#define MDIM   4096
#define NSTEPS 199
#define NBLK   256     // one block per CU
#define NTHR   1024    // 16 waves
#define B1C    0.9f
#define B2C    0.999f
#define EPSC   1e-8f

typedef unsigned long long u64;

// ---------------------------------------------------------------------------
// Prep: Qs[i][j] = 0.5*(va[i][j] + va[j][i]), LDS-tiled transpose (validated).
// ---------------------------------------------------------------------------
__global__ void prep_qs(const float* __restrict__ va, float* __restrict__ Qs) {
    __shared__ float tile[32][33];
    const int j0 = blockIdx.x * 32;
    const int i0 = blockIdx.y * 32;
    const int tx = threadIdx.x, ty = threadIdx.y;

    for (int k = 0; k < 32; k += 8)
        tile[ty + k][tx] = va[(size_t)(j0 + ty + k) * MDIM + i0 + tx];
    __syncthreads();
    for (int k = 0; k < 32; k += 8) {
        int i = i0 + ty + k;
        float a = va[(size_t)i * MDIM + j0 + tx];
        float b = tile[tx][ty + k];          // va[j][i]
        Qs[(size_t)i * MDIM + j0 + tx] = 0.5f * (a + b);
    }
}

// ---------------------------------------------------------------------------
// Init: u0 = 1 - mean; zero flags and go words (per-step slots, no reset races).
// ---------------------------------------------------------------------------
__global__ void init_state(const float* __restrict__ mean,
                           float* __restrict__ u0,
                           int* __restrict__ flags, int nflags) {
    int i = blockIdx.x * blockDim.x + threadIdx.x;
    if (i < MDIM)   u0[i] = 1.0f - mean[i];
    if (i < nflags) flags[i] = 0;
}

// ---------------------------------------------------------------------------
// Persistent cooperative kernel.
// Wave w of block b holds Q[16b..16b+15][256w+4*lane .. +3] in 64 regs/lane.
// Per step:
//   - segment dot entirely from registers (u values loaded as 2x8B agent
//     atomics last step; 16 B/lane = block's minimal 16 KB u traffic),
//   - 34-shuffle fold + 16x17 LDS partial matrix (validated in round 2),
//   - Adam state and u[row] in registers,
//   - publish u[row] (4B agent store), __syncthreads drains it (vmcnt(0)
//     before s_barrier -> release ordering for the flag),
//   - HIERARCHICAL barrier: block 0's wave 0 polls the 256 flags (the only
//     poller on those 8 lines), then stores go[t]; all other blocks poll
//     go[t] with ONE lane (255 single-line loads/round grid-wide, ~30x less
//     poll traffic than the flat poll -> less coherence-point congestion).
// ---------------------------------------------------------------------------
__global__ __launch_bounds__(NTHR) void adam_persist(
        const float* __restrict__ Qs,
        float* u0, float* u1,
        const float* __restrict__ mean,
        float* __restrict__ w_out,
        int* __restrict__ flags, int* __restrict__ go) {
    __shared__ float pr[2][16][17];   // [buf][wave][local row], +1 pad

    const int tid  = threadIdx.x;
    const int bid  = blockIdx.x;
    const int wave = tid >> 6;
    const int lane = tid & 63;
    const int row  = bid * 16 + wave;
    const int col0 = wave * 256 + lane * 4;    // this lane's 4-element segment

    // ---- one-time: Q fragment -> registers (64 regs/lane) ----
    float4 qreg[16];
#pragma unroll
    for (int r = 0; r < 16; ++r)
        qreg[r] = *(const float4*)(Qs + (size_t)(bid * 16 + r) * MDIM + col0);

    float m = 0.0f, v = 0.0f, b1p = 1.0f, b2p = 1.0f;
    const float mrow = mean[row];
    float ucur = 1.0f - mrow;                  // u[row] lives in registers

    // ---- u_{t-1} segment in registers; prologue loads u_0 ----
    float uv0, uv1, uv2, uv3;
    {
        u64 d0 = __hip_atomic_load((const u64*)(u0 + col0),     __ATOMIC_RELAXED, __HIP_MEMORY_SCOPE_AGENT);
        u64 d1 = __hip_atomic_load((const u64*)(u0 + col0 + 2), __ATOMIC_RELAXED, __HIP_MEMORY_SCOPE_AGENT);
        uv0 = __uint_as_float((unsigned)d0);  uv1 = __uint_as_float((unsigned)(d0 >> 32));
        uv2 = __uint_as_float((unsigned)d1);  uv3 = __uint_as_float((unsigned)(d1 >> 32));
    }

    for (int t = 1; t <= NSTEPS; ++t) {
        float* uout = (t & 1) ? u1 : u0;       // u_t lands in buffer t&1
        const int b = t & 1;

        // ---- 16 row-partials over this lane's 4 columns ----
        float acc[16];
#pragma unroll
        for (int r = 0; r < 16; ++r) {
            float4 q = qreg[r];
            acc[r] = q.x * uv0 + q.y * uv1 + q.z * uv2 + q.w * uv3;
        }

        // ---- fold 16 values x 64 lanes -> 1 value/lane (30 shuffles) ----
#pragma unroll
        for (int stage = 0; stage < 4; ++stage) {
            const int mask = 32 >> stage;
            const int half = 8 >> stage;
            const bool hi = (lane & mask) != 0;
#pragma unroll
            for (int i = 0; i < half; ++i) {
                float plo = __shfl_xor(acc[i],        mask);
                float phi = __shfl_xor(acc[i + half], mask);
                acc[i] = hi ? (acc[i + half] + phi) : (acc[i] + plo);
            }
        }
        float acc0 = acc[0];
        acc0 += __shfl_xor(acc0, 1);   // finish sum within the quad
        acc0 += __shfl_xor(acc0, 2);

        if ((lane & 3) == 0) pr[b][wave][lane >> 2] = acc0;
        __syncthreads();               // B1: pr matrix ready

        // ---- cross-wave fold: wave w reduces local row w; Adam in regs ----
        float unew = ucur;
        if (lane < 16) {
            float p = pr[b][lane][wave];
            p += __shfl_xor(p, 1);
            p += __shfl_xor(p, 2);
            p += __shfl_xor(p, 4);
            p += __shfl_xor(p, 8);
            const float g = p;

            b1p *= B1C;
            b2p *= B2C;
            m = B1C * m + (1.0f - B1C) * g;
            v = B2C * v + (1.0f - B2C) * g * g;
            const float denom = sqrtf(v) / sqrtf(1.0f - b2p) + EPSC;
            unew = ucur - (0.1f / (1.0f - b1p)) * m / denom;
            ucur = unew;
        }

        if (t < NSTEPS) {              // nobody consumes u_199 from memory
            if (lane == 0)
                __hip_atomic_store(uout + row, unew, __ATOMIC_RELAXED,
                                   __HIP_MEMORY_SCOPE_AGENT);
            // drains the publish store (s_waitcnt vmcnt(0) before s_barrier)
            // -> release ordering for the flag below.
            __syncthreads();           // B2

            if (tid == 0)
                __hip_atomic_store(flags + t * NBLK + bid, 1, __ATOMIC_RELAXED,
                                   __HIP_MEMORY_SCOPE_AGENT);

            if (bid == 0) {
                // aggregator: sole poller of the 256 flags (8 lines)
                if (tid < 64) {
                    const u64* f64 = (const u64*)(flags + t * NBLK);
                    const u64 PAIR = 0x0000000100000001ULL;
                    int spin = 0;
                    for (;;) {
                        u64 a = __hip_atomic_load(f64 + lane,      __ATOMIC_RELAXED, __HIP_MEMORY_SCOPE_AGENT);
                        u64 c = __hip_atomic_load(f64 + lane + 64, __ATOMIC_RELAXED, __HIP_MEMORY_SCOPE_AGENT);
                        if (__all((a == PAIR) & (c == PAIR))) break;
                        if (++spin > (1 << 24)) break;   // fail visibly, never hang
                    }
                    if (tid == 0)
                        __hip_atomic_store(go + t, 1, __ATOMIC_RELAXED,
                                           __HIP_MEMORY_SCOPE_AGENT);
                }
            } else {
                // one lane per block polls the single go line
                if (tid == 0) {
                    int spin = 0;
                    while (__hip_atomic_load(go + t, __ATOMIC_RELAXED,
                                             __HIP_MEMORY_SCOPE_AGENT) == 0) {
                        if (++spin > (1 << 24)) break;   // fail visibly, never hang
                    }
                }
            }
            __syncthreads();           // B3: go observed -> u_t fully visible

            // ---- load u_t segment for the next iteration (2x8B, 16 B/lane) ----
            u64 d0 = __hip_atomic_load((const u64*)(uout + col0),     __ATOMIC_RELAXED, __HIP_MEMORY_SCOPE_AGENT);
            u64 d1 = __hip_atomic_load((const u64*)(uout + col0 + 2), __ATOMIC_RELAXED, __HIP_MEMORY_SCOPE_AGENT);
            uv0 = __uint_as_float((unsigned)d0);  uv1 = __uint_as_float((unsigned)(d0 >> 32));
            uv2 = __uint_as_float((unsigned)d1);  uv3 = __uint_as_float((unsigned)(d1 >> 32));
        }
    }

    if (lane == 0) w_out[row] = ucur + mrow;
}

extern "C" void kernel_launch(void* const* d_in, const int* in_sizes, int n_in,
                              void* d_out, int out_size, void* d_ws, size_t ws_size,
                              hipStream_t stream) {
    const float* mean = (const float*)d_in[0];   // (4096,)
    const float* va   = (const float*)d_in[1];   // (4096,4096)
    float* w_out = (float*)d_out;                // (4096,)

    float* ws = (float*)d_ws;
    float* Qs  = ws;                              // 64 MB
    float* u0  = ws + (size_t)MDIM * MDIM;        // 16 KB
    float* u1  = u0 + MDIM;                       // 16 KB
    int*   flg = (int*)(u1 + MDIM);               // (NSTEPS+1)*256 ints
    int*   go  = flg + (NSTEPS + 1) * NBLK;       // (NSTEPS+1) ints

    const int nflags = (NSTEPS + 1) * NBLK + (NSTEPS + 1);

    prep_qs<<<dim3(MDIM / 32, MDIM / 32), dim3(32, 8), 0, stream>>>(va, Qs);
    init_state<<<(nflags + 255) / 256, 256, 0, stream>>>(mean, u0, flg, nflags);

    void* args[] = { (void*)&Qs, (void*)&u0, (void*)&u1,
                     (void*)&mean, (void*)&w_out, (void*)&flg, (void*)&go };
    hipLaunchCooperativeKernel((const void*)adam_persist,
                               dim3(NBLK), dim3(NTHR), args, 0, stream);
}